// Round 11
// baseline (158.666 us; speedup 1.0000x reference)
//
#include <hip/hip_runtime.h>
#include <hip/hip_bf16.h>

// B=2, T=2048, C=1024, H=16, D=64. bf16 in/out (runtime dtype detect, inline per block).
// k_prep (768 blocks: transpose w; fp32 path converts x) ->
// k_gemm_qkv v2: 256x256 tile, BK=32, 8 waves/512thr, depth-2 global_load_lds
// pipeline with COUNTED vmcnt (never 0 in loop) + raw s_barrier (T3/T4: the
// compiler's vmcnt(0)-drain before __syncthreads is the m97 ~20% stall; counted
// vmcnt keeps next-next tile's loads in flight across barriers). Both-sides XOR
// swizzle (4-chunk: src chunk (ci&3)^(row&3), linear gl_lds dest, read slot
// quad^(l16&3)) -> conflict-minimal ds_read_b128. Q -> qk rows, K -> K2
// FRAGMENT-ORDER, V -> V2 FRAGMENT-ORDER (unchanged formulas).
// -> k_attn v10 (unchanged): zero staging, zero in-loop barriers, fragment-order
// 1KB wave bursts, split-kv + additive fixed-max merge.
// R5 lesson: never bound-squeeze VGPR (spill=3x). R7: per-lane scattered frags
// are latency-bound; gl_lds DMA + full-phase cover is the fix.
// ws: xb@0(8MB); wt@8MB(6MB); qk@16MB(16MB); K2@32MB(8MB); V2@40MB(8MB)

#define CDIM  1024
#define C3    3072
#define HS    64
#define TLEN  2048
#define KVT   64         // attn kv per trip
#define SCL   0.1803368801111204f   // (1/8) * log2(e)

typedef __attribute__((ext_vector_type(8))) short bf16x8;
typedef __attribute__((ext_vector_type(4))) float f32x4;
typedef __attribute__((ext_vector_type(4))) unsigned short u16x4;

__device__ __forceinline__ unsigned short f2b(float f) {
    unsigned u = __float_as_uint(f);
    unsigned r = (u + 0x7FFFu + ((u >> 16) & 1u)) >> 16;
    return (unsigned short)r;
}
__device__ __forceinline__ float b2f(unsigned short u) {
    return __uint_as_float(((unsigned)u) << 16);
}
__device__ __forceinline__ float fexp2(float x) {
    return __builtin_amdgcn_exp2f(x);
}
__device__ __forceinline__ unsigned pkbf(float a, float b) {
    float2 f; f.x = a; f.y = b;
    __hip_bfloat162 h = __float22bfloat162_rn(f);
    union { __hip_bfloat162 h2; unsigned u; } c;
    c.h2 = h;
    return c.u;
}
__device__ __forceinline__ void gl_lds16(const unsigned short* g, unsigned short* l) {
    __builtin_amdgcn_global_load_lds((const __attribute__((address_space(1))) void*)g,
                                     (__attribute__((address_space(3))) void*)l, 16, 0, 0);
}
// bf16 iff "exponent" bits of low halfword concentrate in the normal range.
__device__ __forceinline__ int detect_bf(const void* bias, int lane) {
    unsigned w = ((const unsigned*)bias)[lane];
    unsigned e = (w >> 7) & 0xFF;
    unsigned long long m = __ballot(e >= 100 && e <= 135);
    return __popcll(m) >= 48;
}

// In-register S^T -> PV-B-fragment exchange.
__device__ __forceinline__ void plswap(unsigned x, unsigned& y0, unsigned& y1) {
    unsigned aa = x, bb = x;
    asm("v_permlane32_swap_b32 %0, %1" : "+v"(aa), "+v"(bb));
    asm("v_permlane16_swap_b32 %0, %1" : "+v"(aa), "+v"(bb));
    y0 = aa; y1 = bb;
}
__device__ __forceinline__ bf16x8 xfrag(unsigned x00, unsigned x01,
                                        unsigned x10, unsigned x11, int qsel) {
    unsigned y000, y100, y001, y101, y010, y110, y011, y111;
    plswap(x00, y000, y100);
    plswap(x01, y001, y101);
    plswap(x10, y010, y110);
    plswap(x11, y011, y111);
    union { unsigned u[4]; bf16x8 v; } r;
    r.u[0] = qsel ? y010 : y000;
    r.u[1] = qsel ? y011 : y001;
    r.u[2] = qsel ? y110 : y100;
    r.u[3] = qsel ? y111 : y101;
    return r.v;
}

// prep: 768 blocks. Each transposes one w tile; fp32 path converts x stripes
// bid, bid+768, bid+1536.
__global__ __launch_bounds__(256) void k_prep(const void* __restrict__ w,
                                              const void* __restrict__ x,
                                              const void* __restrict__ bias,
                                              unsigned short* __restrict__ wt,
                                              unsigned short* __restrict__ xb) {
    __shared__ unsigned short tile[64 * 66];
    int t = threadIdx.x;
    int isbf = detect_bf(bias, t & 63);
    int bid = blockIdx.x;

    {
        int n0 = (bid % 48) * 64;
        int k0 = (bid / 48) * 64;
        for (int i = 0; i < 16; ++i) {
            int idx = t + i * 256;
            int r = idx >> 6, c = idx & 63;
            unsigned short v;
            if (isbf) v = ((const unsigned short*)w)[(k0 + r) * C3 + n0 + c];
            else      v = f2b(((const float*)w)[(k0 + r) * C3 + n0 + c]);
            tile[r * 66 + c] = v;
        }
        __syncthreads();
        for (int i = 0; i < 16; ++i) {
            int idx = t + i * 256;
            int r = idx >> 6, c = idx & 63;
            wt[(n0 + r) * CDIM + k0 + c] = tile[c * 66 + r];
        }
    }
    if (!isbf) {
        const float* s = (const float*)x;
        unsigned* d = (unsigned*)xb;
        for (int sb = bid; sb < 2048; sb += 768) {
            int base = sb * 1024;
            for (int j = t; j < 1024; j += 256) {
                int idx = base + j;
                float a = s[2 * idx], b = s[2 * idx + 1];
                d[idx] = (unsigned)f2b(a) | ((unsigned)f2b(b) << 16);
            }
        }
    }
}

// GEMM v2: qkv = x @ w + bias. 256x256 tile, BK=32, 8 waves (2Mx4N), 512 thr.
// Depth-2 gl_lds pipeline, counted vmcnt(4), raw s_barrier (2/K-step).
// LDS 64KB: As[2][256*32] + Bs[2][256*32], both-sides XOR-4 swizzle.
// Grid 192 blocks (16 m-tiles x 12 n-tiles), XCD-bijective swizzle (192%8==0).
__global__ __launch_bounds__(512, 2) void k_gemm_qkv(const void* __restrict__ xraw,
                                                     const unsigned short* __restrict__ xb,
                                                     const void* __restrict__ biasraw,
                                                     const unsigned short* __restrict__ Bt,
                                                     unsigned short* __restrict__ qk,
                                                     unsigned short* __restrict__ k2,
                                                     unsigned short* __restrict__ v2) {
    __shared__ __align__(16) unsigned short As[2 * 256 * 32];   // 32KB
    __shared__ __align__(16) unsigned short Bs[2 * 256 * 32];   // 32KB
    int tid  = threadIdx.x;
    int lane = tid & 63, wv = tid >> 6;            // wv 0..7
    int quad = lane >> 4, l16 = lane & 15;
    int isbf = detect_bf(biasraw, lane);
    const unsigned short* A = isbf ? (const unsigned short*)xraw : xb;

    // XCD-aware bijective swizzle: 192 blocks, 8 XCDs, 24 per XCD chunk.
    int lin = blockIdx.x;
    int swz = (lin & 7) * 24 + (lin >> 3);
    int m0 = (swz / 12) * 256, n0 = (swz % 12) * 256;
    int wr = wv >> 2, wc = wv & 3;                 // wave row/col in 2x4 grid

    f32x4 acc[8][4] = {};

    // staging map: tile = 256 rows x 32 cols (64B = 4 chunks of 16B); 1024 chunks,
    // 2 per thread (ci, ci+512). Linear LDS dest chunk ci; global source chunk
    // pre-swizzled: gc = (ci&3) ^ (row&3). Wave-uniform-base + lane*16B holds.
    int ci0 = tid,        r0 = ci0 >> 2, g0 = ((ci0 & 3) ^ (r0 & 3)) * 8;
    int ci1 = tid + 512,  r1 = ci1 >> 2, g1 = ((ci1 & 3) ^ (r1 & 3)) * 8;
    const unsigned short* a0 = A  + (m0 + r0) * CDIM + g0;
    const unsigned short* a1 = A  + (m0 + r1) * CDIM + g1;
    const unsigned short* b0 = Bt + (n0 + r0) * CDIM + g0;
    const unsigned short* b1 = Bt + (n0 + r1) * CDIM + g1;
    unsigned short* dA0 = As + ci0 * 8;
    unsigned short* dA1 = As + ci1 * 8;
    unsigned short* dB0 = Bs + ci0 * 8;
    unsigned short* dB1 = Bs + ci1 * 8;

    // trip-invariant fragment read offsets (shorts)
    int sw4 = l16 & 3;
    int aro = (wr * 128 + l16) * 32 + ((quad ^ sw4) * 8);
    int bro = (wc * 64  + l16) * 32 + ((quad ^ sw4) * 8);

    // prologue: stage K-tiles 0 and 1
    {
        gl_lds16(a0,       &As[0 * 8192] + ci0 * 8 - (As - As));   // buf0
        gl_lds16(a1,       dA1);
        gl_lds16(b0,       dB0);
        gl_lds16(b1,       dB1);
        gl_lds16(a0 + 32,  dA0 + 8192);
        gl_lds16(a1 + 32,  dA1 + 8192);
        gl_lds16(b0 + 32,  dB0 + 8192);
        gl_lds16(b1 + 32,  dB1 + 8192);
    }
    asm volatile("s_waitcnt vmcnt(4)" ::: "memory");   // tile 0 landed; tile 1 in flight
    __builtin_amdgcn_s_barrier();

    #pragma unroll 2
    for (int kt = 0; kt < 32; ++kt) {
        int cur = kt & 1;
        const unsigned short* Ac = As + cur * 8192;
        const unsigned short* Bc = Bs + cur * 8192;

        bf16x8 af[8], bfv[4];
        #pragma unroll
        for (int mt = 0; mt < 8; ++mt)
            af[mt] = *(const bf16x8*)&Ac[aro + mt * 512];
        #pragma unroll
        for (int nt = 0; nt < 4; ++nt)
            bfv[nt] = *(const bf16x8*)&Bc[bro + nt * 512];

        __builtin_amdgcn_s_setprio(1);
        #pragma unroll
        for (int mt = 0; mt < 8; ++mt)
            #pragma unroll
            for (int nt = 0; nt < 4; ++nt)
                acc[mt][nt] = __builtin_amdgcn_mfma_f32_16x16x32_bf16(af[mt], bfv[nt], acc[mt][nt], 0, 0, 0);
        __builtin_amdgcn_s_setprio(0);

        __builtin_amdgcn_s_barrier();      // all waves done reading buf[cur]
        if (kt < 30) {
            int koff = (kt + 2) * 32;
            unsigned short* tA = As + cur * 8192;
            unsigned short* tB = Bs + cur * 8192;
            gl_lds16(a0 + koff, tA + ci0 * 8);
            gl_lds16(a1 + koff, tA + ci1 * 8);
            gl_lds16(b0 + koff, tB + ci0 * 8);
            gl_lds16(b1 + koff, tB + ci1 * 8);
            asm volatile("s_waitcnt vmcnt(4)" ::: "memory");  // tile kt+1 landed
        } else {
            asm volatile("s_waitcnt vmcnt(0)" ::: "memory");  // tail: drain
        }
        __builtin_amdgcn_s_barrier();      // buf[cur^1] = tile kt+1 visible to all
    }

    // epilogue: three output regions (block is entirely in one: 256 | 1024)
    if (n0 < 1024) {
        for (int mt = 0; mt < 8; ++mt) {
            int row = m0 + wr * 128 + mt * 16 + quad * 4;
            for (int nt = 0; nt < 4; ++nt) {
                int col = n0 + wc * 64 + nt * 16 + l16;
                float bv = isbf ? b2f(((const unsigned short*)biasraw)[col])
                                : ((const float*)biasraw)[col];
                for (int i = 0; i < 4; ++i)
                    qk[(row + i) * 2048 + col] = f2b(acc[mt][nt][i] + bv);
            }
        }
    } else if (n0 < 2048) {
        for (int mt = 0; mt < 8; ++mt) {
            int row = m0 + wr * 128 + mt * 16 + quad * 4;
            int tq = row & 2047, b = row >> 11;
            for (int nt = 0; nt < 4; ++nt) {
                int col = n0 + wc * 64 + nt * 16 + l16;
                float bv = isbf ? b2f(((const unsigned short*)biasraw)[col])
                                : ((const float*)biasraw)[col];
                int c = col - 1024;
                int hh = c >> 6, d = c & 63;
                int base = ((b * 16 + hh) * 32 + (tq >> 6)) * 4096
                         + ((tq >> 5) & 1) * 2048 + ((tq >> 4) & 1) * 1024
                         + (d >> 5) * 512 + ((d >> 3) & 3) * 128
                         + (tq & 15) * 8 + (d & 7);
                for (int i = 0; i < 4; ++i)
                    k2[base + i * 8] = f2b(acc[mt][nt][i] + bv);
            }
        }
    } else {
        for (int mt = 0; mt < 8; ++mt) {
            int row = m0 + wr * 128 + mt * 16 + quad * 4;
            int tq = row & 2047, b = row >> 11;
            for (int nt = 0; nt < 4; ++nt) {
                int col = n0 + wc * 64 + nt * 16 + l16;
                float bv = isbf ? b2f(((const unsigned short*)biasraw)[col])
                                : ((const float*)biasraw)[col];
                int c = col - 2048;
                int hh = c >> 6, d = c & 63;
                int base = ((b * 16 + hh) * 32 + (tq >> 6)) * 4096
                         + ((tq >> 5) & 1) * 2048 + (d >> 4) * 512
                         + ((tq >> 3) & 3) * 128 + (d & 15) * 8 + (tq & 7);
                u16x4 pk;
                for (int i = 0; i < 4; ++i) pk[i] = f2b(acc[mt][nt][i] + bv);
                *(u16x4*)&v2[base] = pk;
            }
        }
    }
}

// Split-kv causal flash attention v10 (unchanged from R10). Grid (32 bh, 32 y),
// 4 waves/block, 256 thr. Zero LDS staging, zero in-loop barriers.
__global__ __launch_bounds__(256, 4) void k_attn(const unsigned short* __restrict__ qk,
                                                 const unsigned short* __restrict__ k2,
                                                 const unsigned short* __restrict__ v2,
                                                 const void* __restrict__ biasraw,
                                                 void* __restrict__ outv) {
    __shared__ __align__(16) float SMf[4416];   // 17664B epilogue merge buffer

    int tid  = threadIdx.x;
    int lane = tid & 63, wv = tid >> 6;            // wv 0..3
    int quad = lane >> 4, l16 = lane & 15;
    int isbf = detect_bf(biasraw, lane);
    int bh = blockIdx.x;
    int g  = 31 - blockIdx.y;                      // longest blocks dispatch first
    int b = bh >> 4, h = bh & 15;
    int rowbase = b * TLEN;

    int s_ = wv >> 1;                              // q sub-band (0/1)
    int p  = wv & 1;                               // kv parity
    int qbase = 64 * g + 32 * s_;
    int T  = g + 1;
    int Tw = T - ((s_ == 0 && p == 1) ? 1 : 0);    // (0,1) skips the diagonal trip
    bool dmw = (p == s_);                          // wave masks on its last trip

    bf16x8 qf[2][2];
    for (int qt = 0; qt < 2; ++qt)
        for (int kh = 0; kh < 2; ++kh)
            qf[qt][kh] = *(const bf16x8*)&qk[(rowbase + qbase + qt * 16 + l16) * 2048
                                            + h * HS + kh * 32 + quad * 8];

    f32x4 o[2][4] = {};
    float ls[2] = {0.f, 0.f};

    const unsigned short* kp = k2 + bh * 131072 + p * 2048 + lane * 8;
    const unsigned short* vp = v2 + bh * 131072 + p * 2048 + lane * 8;

    bf16x8 kf00, kf01, kf10, kf11;
    if (Tw > 0) {
        kf00 = *(const bf16x8*)kp;
        kf01 = *(const bf16x8*)(kp + 512);
        kf10 = *(const bf16x8*)(kp + 1024);
        kf11 = *(const bf16x8*)(kp + 1536);
        kp += 4096;
    }

    for (int t = 0; t < Tw; ++t) {
        bf16x8 av0 = *(const bf16x8*)vp;
        bf16x8 av1 = *(const bf16x8*)(vp + 512);
        bf16x8 av2 = *(const bf16x8*)(vp + 1024);
        bf16x8 av3 = *(const bf16x8*)(vp + 1536);
        vp += 4096;

        f32x4 sv[2][2];
        __builtin_amdgcn_s_setprio(1);
        #pragma unroll
        for (int qt = 0; qt < 2; ++qt) {
            f32x4 z0 = {};
            z0 = __builtin_amdgcn_mfma_f32_16x16x32_bf16(kf00, qf[qt][0], z0, 0, 0, 0);
            z0 = __builtin_amdgcn_mfma_f32_16x16x32_bf16(kf01, qf[qt][1], z0, 0, 0, 0);
            sv[qt][0] = z0;
            f32x4 z1 = {};
            z1 = __builtin_amdgcn_mfma_f32_16x16x32_bf16(kf10, qf[qt][0], z1, 0, 0, 0);
            z1 = __builtin_amdgcn_mfma_f32_16x16x32_bf16(kf11, qf[qt][1], z1, 0, 0, 0);
            sv[qt][1] = z1;
        }
        __builtin_amdgcn_s_setprio(0);

        bool pf = (t + 1 < Tw);
        bf16x8 kn00 = *(const bf16x8*)kp;
        bf16x8 kn01 = *(const bf16x8*)(kp + 512);
        bf16x8 kn10 = *(const bf16x8*)(kp + 1024);
        bf16x8 kn11 = *(const bf16x8*)(kp + 1536);
        kp += 4096;

        unsigned sp[2][2][2];
        int kvb = t * KVT + 32 * p;
        if (dmw && (t == T - 1)) {
            #pragma unroll
            for (int qt = 0; qt < 2; ++qt) {
                float psum = 0.f;
                int q = qbase + qt * 16 + l16;
                #pragma unroll
                for (int nt = 0; nt < 2; ++nt) {
                    float pv[4];
                    #pragma unroll
                    for (int i = 0; i < 4; ++i) {
                        float arg = fmaf(sv[qt][nt][i], SCL, -12.0f);
                        int kv = kvb + nt * 16 + quad * 4 + i;
                        if (kv > q) arg = -1e30f;
                        pv[i] = fexp2(arg);
                        psum += pv[i];
                    }
                    sp[qt][nt][0] = pkbf(pv[0], pv[1]);
                    sp[qt][nt][1] = pkbf(pv[2], pv[3]);
                }
                ls[qt] += psum;
            }
        } else {
            #pragma unroll
            for (int qt = 0; qt < 2; ++qt) {
                float psum = 0.f;
                #pragma unroll
                for (int nt = 0; nt < 2; ++nt) {
                    float pv[4];
                    #pragma unroll
                    for (int i = 0; i < 4; ++i) {
                        float arg = fmaf(sv[qt][nt][i], SCL, -12.0f);
                        pv[i] = fexp2(arg);
                        psum += pv[i];
                    }
                    sp[qt][nt][0] = pkbf(pv[0], pv[1]);
                    sp[qt][nt][1] = pkbf(pv[2], pv[3]);
                }
                ls[qt] += psum;
            }
        }

        int qsel = quad & 2;
        bf16x8 f0 = xfrag(sp[0][0][0], sp[0][0][1], sp[0][1][0], sp[0][1][1], qsel);
        bf16x8 f1 = xfrag(sp[1][0][0], sp[1][0][1], sp[1][1][0], sp[1][1][1], qsel);
        __builtin_amdgcn_s_setprio(1);
        o[0][0] = __builtin_amdgcn_mfma_f32_16x16x32_bf16(av0, f0, o[0][0], 0, 0, 0);
        o[1][0] = __builtin_amdgcn_mfma_f32_16x16x32_bf16(av0, f1, o[1][0], 0, 0, 0);
        o[0][1] = __builtin_amdgcn_mfma_f32_16x16x32_bf16(av1, f0, o[0][1], 0, 0, 0);
        o[1][1] = __builtin_amdgcn_mfma_f32_16x16x32_bf16(av1, f1, o[1][1], 0, 0, 0);
        o[0][2] = __builtin_amdgcn_mfma_f32_16x16x32_bf16(av2, f0, o[0][2], 0, 0, 0);
        o[1][2] = __builtin_amdgcn_mfma_f32_16x16x32_bf16(av2, f1, o[1][2], 0, 0, 0);
        o[0][3] = __builtin_amdgcn_mfma_f32_16x16x32_bf16(av3, f0, o[0][3], 0, 0, 0);
        o[1][3] = __builtin_amdgcn_mfma_f32_16x16x32_bf16(av3, f1, o[1][3], 0, 0, 0);
        __builtin_amdgcn_s_setprio(0);

        if (pf) { kf00 = kn00; kf01 = kn01; kf10 = kn10; kf11 = kn11; }
    }

    #pragma unroll
    for (int qt = 0; qt < 2; ++qt) {
        ls[qt] += __shfl_xor(ls[qt], 16);
        ls[qt] += __shfl_xor(ls[qt], 32);
    }
    float* mrg  = SMf;
    float* lbuf = SMf + 4352;

    if (p == 1) {
        #pragma unroll
        for (int qt = 0; qt < 2; ++qt)
            #pragma unroll
            for (int dt = 0; dt < 4; ++dt)
                *(f32x4*)&mrg[s_ * (32 * 68) + (qt * 16 + l16) * 68 + dt * 16 + quad * 4] = o[qt][dt];
        if (quad == 0) {
            lbuf[s_ * 32 + l16]      = ls[0];
            lbuf[s_ * 32 + 16 + l16] = ls[1];
        }
    }
    __syncthreads();
    if (p == 0) {
        #pragma unroll
        for (int qt = 0; qt < 2; ++qt) {
            float lt = ls[qt] + lbuf[s_ * 32 + qt * 16 + l16];
            float inv = 1.0f / lt;
            int q = qbase + qt * 16 + l16;
            if (isbf) {
                unsigned short* out = (unsigned short*)outv;
                #pragma unroll
                for (int dt = 0; dt < 4; ++dt) {
                    f32x4 m = *(const f32x4*)&mrg[s_ * (32 * 68) + (qt * 16 + l16) * 68 + dt * 16 + quad * 4];
                    u16x4 ov;
                    #pragma unroll
                    for (int i = 0; i < 4; ++i) ov[i] = f2b((o[qt][dt][i] + m[i]) * inv);
                    *(u16x4*)&out[(rowbase + q) * CDIM + h * HS + dt * 16 + quad * 4] = ov;
                }
            } else {
                float* out = (float*)outv;
                #pragma unroll
                for (int dt = 0; dt < 4; ++dt) {
                    f32x4 m = *(const f32x4*)&mrg[s_ * (32 * 68) + (qt * 16 + l16) * 68 + dt * 16 + quad * 4];
                    float4 ov;
                    ov.x = (o[qt][dt][0] + m[0]) * inv;
                    ov.y = (o[qt][dt][1] + m[1]) * inv;
                    ov.z = (o[qt][dt][2] + m[2]) * inv;
                    ov.w = (o[qt][dt][3] + m[3]) * inv;
                    *(float4*)&out[(rowbase + q) * CDIM + h * HS + dt * 16 + quad * 4] = ov;
                }
            }
        }
    }
}

extern "C" void kernel_launch(void* const* d_in, const int* in_sizes, int n_in,
                              void* d_out, int out_size, void* d_ws, size_t ws_size,
                              hipStream_t stream) {
    const void* x    = d_in[0];
    const void* w    = d_in[1];
    const void* bias = d_in[2];

    char* ws = (char*)d_ws;
    unsigned short* xb  = (unsigned short*)ws;                   // 8 MB (fp32 path only)
    unsigned short* wt  = (unsigned short*)(ws + (8u  << 20));   // 6 MB
    unsigned short* qk  = (unsigned short*)(ws + (16u << 20));   // 16 MB (Q rows)
    unsigned short* k2  = (unsigned short*)(ws + (32u << 20));   // 8 MB (K fragment-order)
    unsigned short* v2  = (unsigned short*)(ws + (40u << 20));   // 8 MB (V fragment-order)

    k_prep<<<768, 256, 0, stream>>>(w, x, bias, wt, xb);
    k_gemm_qkv<<<192, 512, 0, stream>>>(x, xb, bias, wt, qk, k2, v2);
    k_attn<<<dim3(32, 32), 256, 0, stream>>>(qk, k2, v2, bias, d_out);
}

// Round 12
// 150.886 us; speedup vs baseline: 1.0516x; 1.0516x over previous
//
#include <hip/hip_runtime.h>
#include <hip/hip_bf16.h>

// B=2, T=2048, C=1024, H=16, D=64. bf16 in/out (runtime dtype detect, inline per block).
// k_prep (768 blocks: transpose w; fp32 path converts x) ->
// k_gemm_qkv v3: 128x128 tile, BK=32, 4 waves/256thr, depth-2 global_load_lds
// pipeline with COUNTED vmcnt(4) (never 0 in loop) + raw s_barrier. R11 lesson:
// the schedule was right but 256^2 gave 192 blocks < 256 CUs (occ 14%); 128^2
// gives 768 blocks = 3 blocks/CU, 32KB LDS dbuf, barrier stalls hidden by
// co-resident blocks. XOR-4 both-sides swizzle (verified conflict-floor in R11:
// SQ_LDS_BANK_CONFLICT = exactly 4 cyc/b128 = phase minimum).
// Q -> qk rows, K -> K2 FRAGMENT-ORDER, V -> V2 FRAGMENT-ORDER (unchanged).
// -> k_attn v10 (unchanged): zero staging, zero in-loop barriers, fragment-order
// 1KB wave bursts, split-kv + additive fixed-max merge.
// R5 lesson: never bound-squeeze VGPR (spill=3x).
// ws: xb@0(8MB); wt@8MB(6MB); qk@16MB(16MB); K2@32MB(8MB); V2@40MB(8MB)

#define CDIM  1024
#define C3    3072
#define HS    64
#define TLEN  2048
#define KVT   64         // attn kv per trip
#define SCL   0.1803368801111204f   // (1/8) * log2(e)

typedef __attribute__((ext_vector_type(8))) short bf16x8;
typedef __attribute__((ext_vector_type(4))) float f32x4;
typedef __attribute__((ext_vector_type(4))) unsigned short u16x4;

__device__ __forceinline__ unsigned short f2b(float f) {
    unsigned u = __float_as_uint(f);
    unsigned r = (u + 0x7FFFu + ((u >> 16) & 1u)) >> 16;
    return (unsigned short)r;
}
__device__ __forceinline__ float b2f(unsigned short u) {
    return __uint_as_float(((unsigned)u) << 16);
}
__device__ __forceinline__ float fexp2(float x) {
    return __builtin_amdgcn_exp2f(x);
}
__device__ __forceinline__ unsigned pkbf(float a, float b) {
    float2 f; f.x = a; f.y = b;
    __hip_bfloat162 h = __float22bfloat162_rn(f);
    union { __hip_bfloat162 h2; unsigned u; } c;
    c.h2 = h;
    return c.u;
}
__device__ __forceinline__ void gl_lds16(const unsigned short* g, unsigned short* l) {
    __builtin_amdgcn_global_load_lds((const __attribute__((address_space(1))) void*)g,
                                     (__attribute__((address_space(3))) void*)l, 16, 0, 0);
}
// bf16 iff "exponent" bits of low halfword concentrate in the normal range.
__device__ __forceinline__ int detect_bf(const void* bias, int lane) {
    unsigned w = ((const unsigned*)bias)[lane];
    unsigned e = (w >> 7) & 0xFF;
    unsigned long long m = __ballot(e >= 100 && e <= 135);
    return __popcll(m) >= 48;
}

// In-register S^T -> PV-B-fragment exchange.
__device__ __forceinline__ void plswap(unsigned x, unsigned& y0, unsigned& y1) {
    unsigned aa = x, bb = x;
    asm("v_permlane32_swap_b32 %0, %1" : "+v"(aa), "+v"(bb));
    asm("v_permlane16_swap_b32 %0, %1" : "+v"(aa), "+v"(bb));
    y0 = aa; y1 = bb;
}
__device__ __forceinline__ bf16x8 xfrag(unsigned x00, unsigned x01,
                                        unsigned x10, unsigned x11, int qsel) {
    unsigned y000, y100, y001, y101, y010, y110, y011, y111;
    plswap(x00, y000, y100);
    plswap(x01, y001, y101);
    plswap(x10, y010, y110);
    plswap(x11, y011, y111);
    union { unsigned u[4]; bf16x8 v; } r;
    r.u[0] = qsel ? y010 : y000;
    r.u[1] = qsel ? y011 : y001;
    r.u[2] = qsel ? y110 : y100;
    r.u[3] = qsel ? y111 : y101;
    return r.v;
}

// prep: 768 blocks. Each transposes one w tile; fp32 path converts x stripes
// bid, bid+768, bid+1536.
__global__ __launch_bounds__(256) void k_prep(const void* __restrict__ w,
                                              const void* __restrict__ x,
                                              const void* __restrict__ bias,
                                              unsigned short* __restrict__ wt,
                                              unsigned short* __restrict__ xb) {
    __shared__ unsigned short tile[64 * 66];
    int t = threadIdx.x;
    int isbf = detect_bf(bias, t & 63);
    int bid = blockIdx.x;

    {
        int n0 = (bid % 48) * 64;
        int k0 = (bid / 48) * 64;
        for (int i = 0; i < 16; ++i) {
            int idx = t + i * 256;
            int r = idx >> 6, c = idx & 63;
            unsigned short v;
            if (isbf) v = ((const unsigned short*)w)[(k0 + r) * C3 + n0 + c];
            else      v = f2b(((const float*)w)[(k0 + r) * C3 + n0 + c]);
            tile[r * 66 + c] = v;
        }
        __syncthreads();
        for (int i = 0; i < 16; ++i) {
            int idx = t + i * 256;
            int r = idx >> 6, c = idx & 63;
            wt[(n0 + r) * CDIM + k0 + c] = tile[c * 66 + r];
        }
    }
    if (!isbf) {
        const float* s = (const float*)x;
        unsigned* d = (unsigned*)xb;
        for (int sb = bid; sb < 2048; sb += 768) {
            int base = sb * 1024;
            for (int j = t; j < 1024; j += 256) {
                int idx = base + j;
                float a = s[2 * idx], b = s[2 * idx + 1];
                d[idx] = (unsigned)f2b(a) | ((unsigned)f2b(b) << 16);
            }
        }
    }
}

// GEMM v3: qkv = x @ w + bias. 128x128 tile, BK=32, 4 waves (2x2), 256 thr.
// Depth-2 gl_lds pipeline, counted vmcnt(4), raw s_barrier (2/K-step).
// LDS 32KB: As[2][128*32] + Bs[2][128*32], both-sides XOR-4 swizzle.
// Grid 768 blocks (32 m x 24 n), XCD-bijective swizzle (768%8==0) -> 3 blocks/CU.
__global__ __launch_bounds__(256, 3) void k_gemm_qkv(const void* __restrict__ xraw,
                                                     const unsigned short* __restrict__ xb,
                                                     const void* __restrict__ biasraw,
                                                     const unsigned short* __restrict__ Bt,
                                                     unsigned short* __restrict__ qk,
                                                     unsigned short* __restrict__ k2,
                                                     unsigned short* __restrict__ v2) {
    __shared__ __align__(16) unsigned short As[2 * 128 * 32];   // 16KB
    __shared__ __align__(16) unsigned short Bs[2 * 128 * 32];   // 16KB
    int tid  = threadIdx.x;
    int lane = tid & 63, wv = tid >> 6;            // wv 0..3
    int quad = lane >> 4, l16 = lane & 15;
    int isbf = detect_bf(biasraw, lane);
    const unsigned short* A = isbf ? (const unsigned short*)xraw : xb;

    // XCD-aware bijective swizzle: 768 blocks, 8 XCDs, 96 per XCD chunk.
    int lin = blockIdx.x + 24 * blockIdx.y;
    int swz = (lin & 7) * 96 + (lin >> 3);
    int m0 = (swz / 24) * 128, n0 = (swz % 24) * 128;
    int wm = (wv >> 1) * 64, wn = (wv & 1) * 64;

    f32x4 acc[4][4] = {};

    // staging map: tile = 128 rows x 32 cols; 512 chunks of 16B per matrix,
    // 2 per thread (rows r0 and r0+64, same in-row chunk). Linear LDS dest
    // chunk ci = tid (and tid+256); global source chunk pre-swizzled:
    // gc = (ci&3) ^ (row&3).  (row+64)&3 == row&3, so both share g0.
    int r0 = tid >> 2;                               // 0..63
    int g0 = (((tid & 3) ^ (r0 & 3)) * 8);
    const unsigned short* a0 = A  + (m0 + r0) * CDIM + g0;
    const unsigned short* b0 = Bt + (n0 + r0) * CDIM + g0;
    unsigned short* dA = As + tid * 8;               // + 2048 for row r0+64
    unsigned short* dB = Bs + tid * 8;

    // trip-invariant fragment read offsets (shorts): slot = quad ^ (row&3)
    int sw4 = l16 & 3;
    int aro = (wm + l16) * 32 + ((quad ^ sw4) * 8);
    int bro = (wn + l16) * 32 + ((quad ^ sw4) * 8);

    // prologue: stage K-tiles 0 (buf0) and 1 (buf1)
    gl_lds16(a0,                 dA);
    gl_lds16(a0 + 64 * CDIM,     dA + 2048);
    gl_lds16(b0,                 dB);
    gl_lds16(b0 + 64 * CDIM,     dB + 2048);
    gl_lds16(a0 + 32,            dA + 4096);
    gl_lds16(a0 + 64 * CDIM + 32, dA + 4096 + 2048);
    gl_lds16(b0 + 32,            dB + 4096);
    gl_lds16(b0 + 64 * CDIM + 32, dB + 4096 + 2048);
    asm volatile("s_waitcnt vmcnt(4)" ::: "memory");   // tile 0 landed; tile 1 in flight
    __builtin_amdgcn_s_barrier();

    #pragma unroll 2
    for (int kt = 0; kt < 32; ++kt) {
        int cur = kt & 1;
        const unsigned short* Ac = As + cur * 4096;
        const unsigned short* Bc = Bs + cur * 4096;

        bf16x8 af[4], bfv[4];
        #pragma unroll
        for (int mt = 0; mt < 4; ++mt)
            af[mt] = *(const bf16x8*)&Ac[aro + mt * 512];
        #pragma unroll
        for (int nt = 0; nt < 4; ++nt)
            bfv[nt] = *(const bf16x8*)&Bc[bro + nt * 512];

        __builtin_amdgcn_s_setprio(1);
        #pragma unroll
        for (int mt = 0; mt < 4; ++mt)
            #pragma unroll
            for (int nt = 0; nt < 4; ++nt)
                acc[mt][nt] = __builtin_amdgcn_mfma_f32_16x16x32_bf16(af[mt], bfv[nt], acc[mt][nt], 0, 0, 0);
        __builtin_amdgcn_s_setprio(0);

        __builtin_amdgcn_s_barrier();      // all waves done reading buf[cur]
        if (kt < 30) {
            int koff = (kt + 2) * 32;
            unsigned short* tA = As + cur * 4096;
            unsigned short* tB = Bs + cur * 4096;
            gl_lds16(a0 + koff,            tA + tid * 8);
            gl_lds16(a0 + 64 * CDIM + koff, tA + tid * 8 + 2048);
            gl_lds16(b0 + koff,            tB + tid * 8);
            gl_lds16(b0 + 64 * CDIM + koff, tB + tid * 8 + 2048);
            asm volatile("s_waitcnt vmcnt(4)" ::: "memory");  // tile kt+1 landed
        } else {
            asm volatile("s_waitcnt vmcnt(0)" ::: "memory");  // tail: drain
        }
        __builtin_amdgcn_s_barrier();      // buf[cur^1] = tile kt+1 visible
    }

    // epilogue: three output regions (128-wide block lies entirely in one)
    if (n0 < 1024) {
        for (int mt = 0; mt < 4; ++mt) {
            int row = m0 + wm + mt * 16 + quad * 4;
            for (int nt = 0; nt < 4; ++nt) {
                int col = n0 + wn + nt * 16 + l16;
                float bv = isbf ? b2f(((const unsigned short*)biasraw)[col])
                                : ((const float*)biasraw)[col];
                for (int i = 0; i < 4; ++i)
                    qk[(row + i) * 2048 + col] = f2b(acc[mt][nt][i] + bv);
            }
        }
    } else if (n0 < 2048) {
        for (int mt = 0; mt < 4; ++mt) {
            int row = m0 + wm + mt * 16 + quad * 4;
            int tq = row & 2047, b = row >> 11;
            for (int nt = 0; nt < 4; ++nt) {
                int col = n0 + wn + nt * 16 + l16;
                float bv = isbf ? b2f(((const unsigned short*)biasraw)[col])
                                : ((const float*)biasraw)[col];
                int c = col - 1024;
                int hh = c >> 6, d = c & 63;
                int base = ((b * 16 + hh) * 32 + (tq >> 6)) * 4096
                         + ((tq >> 5) & 1) * 2048 + ((tq >> 4) & 1) * 1024
                         + (d >> 5) * 512 + ((d >> 3) & 3) * 128
                         + (tq & 15) * 8 + (d & 7);
                for (int i = 0; i < 4; ++i)
                    k2[base + i * 8] = f2b(acc[mt][nt][i] + bv);
            }
        }
    } else {
        for (int mt = 0; mt < 4; ++mt) {
            int row = m0 + wm + mt * 16 + quad * 4;
            int tq = row & 2047, b = row >> 11;
            for (int nt = 0; nt < 4; ++nt) {
                int col = n0 + wn + nt * 16 + l16;
                float bv = isbf ? b2f(((const unsigned short*)biasraw)[col])
                                : ((const float*)biasraw)[col];
                int c = col - 2048;
                int hh = c >> 6, d = c & 63;
                int base = ((b * 16 + hh) * 32 + (tq >> 6)) * 4096
                         + ((tq >> 5) & 1) * 2048 + (d >> 4) * 512
                         + ((tq >> 3) & 3) * 128 + (d & 15) * 8 + (tq & 7);
                u16x4 pk;
                for (int i = 0; i < 4; ++i) pk[i] = f2b(acc[mt][nt][i] + bv);
                *(u16x4*)&v2[base] = pk;
            }
        }
    }
}

// Split-kv causal flash attention v10 (unchanged). Grid (32 bh, 32 y),
// 4 waves/block, 256 thr. Zero LDS staging, zero in-loop barriers.
__global__ __launch_bounds__(256, 4) void k_attn(const unsigned short* __restrict__ qk,
                                                 const unsigned short* __restrict__ k2,
                                                 const unsigned short* __restrict__ v2,
                                                 const void* __restrict__ biasraw,
                                                 void* __restrict__ outv) {
    __shared__ __align__(16) float SMf[4416];   // 17664B epilogue merge buffer

    int tid  = threadIdx.x;
    int lane = tid & 63, wv = tid >> 6;            // wv 0..3
    int quad = lane >> 4, l16 = lane & 15;
    int isbf = detect_bf(biasraw, lane);
    int bh = blockIdx.x;
    int g  = 31 - blockIdx.y;                      // longest blocks dispatch first
    int b = bh >> 4, h = bh & 15;
    int rowbase = b * TLEN;

    int s_ = wv >> 1;                              // q sub-band (0/1)
    int p  = wv & 1;                               // kv parity
    int qbase = 64 * g + 32 * s_;
    int T  = g + 1;
    int Tw = T - ((s_ == 0 && p == 1) ? 1 : 0);    // (0,1) skips the diagonal trip
    bool dmw = (p == s_);                          // wave masks on its last trip

    bf16x8 qf[2][2];
    for (int qt = 0; qt < 2; ++qt)
        for (int kh = 0; kh < 2; ++kh)
            qf[qt][kh] = *(const bf16x8*)&qk[(rowbase + qbase + qt * 16 + l16) * 2048
                                            + h * HS + kh * 32 + quad * 8];

    f32x4 o[2][4] = {};
    float ls[2] = {0.f, 0.f};

    const unsigned short* kp = k2 + bh * 131072 + p * 2048 + lane * 8;
    const unsigned short* vp = v2 + bh * 131072 + p * 2048 + lane * 8;

    bf16x8 kf00, kf01, kf10, kf11;
    if (Tw > 0) {
        kf00 = *(const bf16x8*)kp;
        kf01 = *(const bf16x8*)(kp + 512);
        kf10 = *(const bf16x8*)(kp + 1024);
        kf11 = *(const bf16x8*)(kp + 1536);
        kp += 4096;
    }

    for (int t = 0; t < Tw; ++t) {
        bf16x8 av0 = *(const bf16x8*)vp;
        bf16x8 av1 = *(const bf16x8*)(vp + 512);
        bf16x8 av2 = *(const bf16x8*)(vp + 1024);
        bf16x8 av3 = *(const bf16x8*)(vp + 1536);
        vp += 4096;

        f32x4 sv[2][2];
        __builtin_amdgcn_s_setprio(1);
        #pragma unroll
        for (int qt = 0; qt < 2; ++qt) {
            f32x4 z0 = {};
            z0 = __builtin_amdgcn_mfma_f32_16x16x32_bf16(kf00, qf[qt][0], z0, 0, 0, 0);
            z0 = __builtin_amdgcn_mfma_f32_16x16x32_bf16(kf01, qf[qt][1], z0, 0, 0, 0);
            sv[qt][0] = z0;
            f32x4 z1 = {};
            z1 = __builtin_amdgcn_mfma_f32_16x16x32_bf16(kf10, qf[qt][0], z1, 0, 0, 0);
            z1 = __builtin_amdgcn_mfma_f32_16x16x32_bf16(kf11, qf[qt][1], z1, 0, 0, 0);
            sv[qt][1] = z1;
        }
        __builtin_amdgcn_s_setprio(0);

        bool pf = (t + 1 < Tw);
        bf16x8 kn00 = *(const bf16x8*)kp;
        bf16x8 kn01 = *(const bf16x8*)(kp + 512);
        bf16x8 kn10 = *(const bf16x8*)(kp + 1024);
        bf16x8 kn11 = *(const bf16x8*)(kp + 1536);
        kp += 4096;

        unsigned sp[2][2][2];
        int kvb = t * KVT + 32 * p;
        if (dmw && (t == T - 1)) {
            #pragma unroll
            for (int qt = 0; qt < 2; ++qt) {
                float psum = 0.f;
                int q = qbase + qt * 16 + l16;
                #pragma unroll
                for (int nt = 0; nt < 2; ++nt) {
                    float pv[4];
                    #pragma unroll
                    for (int i = 0; i < 4; ++i) {
                        float arg = fmaf(sv[qt][nt][i], SCL, -12.0f);
                        int kv = kvb + nt * 16 + quad * 4 + i;
                        if (kv > q) arg = -1e30f;
                        pv[i] = fexp2(arg);
                        psum += pv[i];
                    }
                    sp[qt][nt][0] = pkbf(pv[0], pv[1]);
                    sp[qt][nt][1] = pkbf(pv[2], pv[3]);
                }
                ls[qt] += psum;
            }
        } else {
            #pragma unroll
            for (int qt = 0; qt < 2; ++qt) {
                float psum = 0.f;
                #pragma unroll
                for (int nt = 0; nt < 2; ++nt) {
                    float pv[4];
                    #pragma unroll
                    for (int i = 0; i < 4; ++i) {
                        float arg = fmaf(sv[qt][nt][i], SCL, -12.0f);
                        pv[i] = fexp2(arg);
                        psum += pv[i];
                    }
                    sp[qt][nt][0] = pkbf(pv[0], pv[1]);
                    sp[qt][nt][1] = pkbf(pv[2], pv[3]);
                }
                ls[qt] += psum;
            }
        }

        int qsel = quad & 2;
        bf16x8 f0 = xfrag(sp[0][0][0], sp[0][0][1], sp[0][1][0], sp[0][1][1], qsel);
        bf16x8 f1 = xfrag(sp[1][0][0], sp[1][0][1], sp[1][1][0], sp[1][1][1], qsel);
        __builtin_amdgcn_s_setprio(1);
        o[0][0] = __builtin_amdgcn_mfma_f32_16x16x32_bf16(av0, f0, o[0][0], 0, 0, 0);
        o[1][0] = __builtin_amdgcn_mfma_f32_16x16x32_bf16(av0, f1, o[1][0], 0, 0, 0);
        o[0][1] = __builtin_amdgcn_mfma_f32_16x16x32_bf16(av1, f0, o[0][1], 0, 0, 0);
        o[1][1] = __builtin_amdgcn_mfma_f32_16x16x32_bf16(av1, f1, o[1][1], 0, 0, 0);
        o[0][2] = __builtin_amdgcn_mfma_f32_16x16x32_bf16(av2, f0, o[0][2], 0, 0, 0);
        o[1][2] = __builtin_amdgcn_mfma_f32_16x16x32_bf16(av2, f1, o[1][2], 0, 0, 0);
        o[0][3] = __builtin_amdgcn_mfma_f32_16x16x32_bf16(av3, f0, o[0][3], 0, 0, 0);
        o[1][3] = __builtin_amdgcn_mfma_f32_16x16x32_bf16(av3, f1, o[1][3], 0, 0, 0);
        __builtin_amdgcn_s_setprio(0);

        if (pf) { kf00 = kn00; kf01 = kn01; kf10 = kn10; kf11 = kn11; }
    }

    #pragma unroll
    for (int qt = 0; qt < 2; ++qt) {
        ls[qt] += __shfl_xor(ls[qt], 16);
        ls[qt] += __shfl_xor(ls[qt], 32);
    }
    float* mrg  = SMf;
    float* lbuf = SMf + 4352;

    if (p == 1) {
        #pragma unroll
        for (int qt = 0; qt < 2; ++qt)
            #pragma unroll
            for (int dt = 0; dt < 4; ++dt)
                *(f32x4*)&mrg[s_ * (32 * 68) + (qt * 16 + l16) * 68 + dt * 16 + quad * 4] = o[qt][dt];
        if (quad == 0) {
            lbuf[s_ * 32 + l16]      = ls[0];
            lbuf[s_ * 32 + 16 + l16] = ls[1];
        }
    }
    __syncthreads();
    if (p == 0) {
        #pragma unroll
        for (int qt = 0; qt < 2; ++qt) {
            float lt = ls[qt] + lbuf[s_ * 32 + qt * 16 + l16];
            float inv = 1.0f / lt;
            int q = qbase + qt * 16 + l16;
            if (isbf) {
                unsigned short* out = (unsigned short*)outv;
                #pragma unroll
                for (int dt = 0; dt < 4; ++dt) {
                    f32x4 m = *(const f32x4*)&mrg[s_ * (32 * 68) + (qt * 16 + l16) * 68 + dt * 16 + quad * 4];
                    u16x4 ov;
                    #pragma unroll
                    for (int i = 0; i < 4; ++i) ov[i] = f2b((o[qt][dt][i] + m[i]) * inv);
                    *(u16x4*)&out[(rowbase + q) * CDIM + h * HS + dt * 16 + quad * 4] = ov;
                }
            } else {
                float* out = (float*)outv;
                #pragma unroll
                for (int dt = 0; dt < 4; ++dt) {
                    f32x4 m = *(const f32x4*)&mrg[s_ * (32 * 68) + (qt * 16 + l16) * 68 + dt * 16 + quad * 4];
                    float4 ov;
                    ov.x = (o[qt][dt][0] + m[0]) * inv;
                    ov.y = (o[qt][dt][1] + m[1]) * inv;
                    ov.z = (o[qt][dt][2] + m[2]) * inv;
                    ov.w = (o[qt][dt][3] + m[3]) * inv;
                    *(float4*)&out[(rowbase + q) * CDIM + h * HS + dt * 16 + quad * 4] = ov;
                }
            }
        }
    }
}

extern "C" void kernel_launch(void* const* d_in, const int* in_sizes, int n_in,
                              void* d_out, int out_size, void* d_ws, size_t ws_size,
                              hipStream_t stream) {
    const void* x    = d_in[0];
    const void* w    = d_in[1];
    const void* bias = d_in[2];

    char* ws = (char*)d_ws;
    unsigned short* xb  = (unsigned short*)ws;                   // 8 MB (fp32 path only)
    unsigned short* wt  = (unsigned short*)(ws + (8u  << 20));   // 6 MB
    unsigned short* qk  = (unsigned short*)(ws + (16u << 20));   // 16 MB (Q rows)
    unsigned short* k2  = (unsigned short*)(ws + (32u << 20));   // 8 MB (K fragment-order)
    unsigned short* v2  = (unsigned short*)(ws + (40u << 20));   // 8 MB (V fragment-order)

    k_prep<<<768, 256, 0, stream>>>(w, x, bias, wt, xb);
    k_gemm_qkv<<<dim3(24, 32), 256, 0, stream>>>(x, xb, bias, wt, qk, k2, v2);
    k_attn<<<dim3(32, 32), 256, 0, stream>>>(qk, k2, v2, bias, d_out);
}

// Round 13
// 148.635 us; speedup vs baseline: 1.0675x; 1.0151x over previous
//
#include <hip/hip_runtime.h>
#include <hip/hip_bf16.h>

// B=2, T=2048, C=1024, H=16, D=64. bf16 in/out (runtime dtype detect, inline per block).
// k_prep (768 blocks: transpose w; fp32 path converts x via float4) ->
// k_gemm_qkv v3 (unchanged from R12): 128x128, BK=32, depth-2 gl_lds pipeline,
// counted vmcnt(4), raw s_barrier, XOR-4 both-sides swizzle, 768 blocks.
// -> k_attn v11: v10 + CROSS-TRIP SOFTWARE PIPELINE: QK(t+1) MFMA issues before
// softmax(t) VALU (K(t+1) frags prefetched a trip earlier -> no load dep), so the
// matrix pipe runs under the softmax/xfrag chain. 2x-unrolled ping-pong svA/svB
// (no register copies). launch_bounds(256,3): +~40 VGPR for the pipeline, cap 168
// (NO squeeze - R5 spill lesson), 3 blocks/CU.
// K2 idx = (bh*32+t)*4096 + p*2048 + nt*1024 + kh*512 + lane*8 + j
// V2 idx = (bh*32+t)*4096 + p*2048 + dt*512 + lane*8 + j
// ws: xb@0(8MB); wt@8MB(6MB); qk@16MB(16MB); K2@32MB(8MB); V2@40MB(8MB)

#define CDIM  1024
#define C3    3072
#define HS    64
#define TLEN  2048
#define KVT   64         // attn kv per trip
#define SCL   0.1803368801111204f   // (1/8) * log2(e)

typedef __attribute__((ext_vector_type(8))) short bf16x8;
typedef __attribute__((ext_vector_type(4))) float f32x4;
typedef __attribute__((ext_vector_type(4))) unsigned short u16x4;

__device__ __forceinline__ unsigned short f2b(float f) {
    unsigned u = __float_as_uint(f);
    unsigned r = (u + 0x7FFFu + ((u >> 16) & 1u)) >> 16;
    return (unsigned short)r;
}
__device__ __forceinline__ float b2f(unsigned short u) {
    return __uint_as_float(((unsigned)u) << 16);
}
__device__ __forceinline__ float fexp2(float x) {
    return __builtin_amdgcn_exp2f(x);
}
__device__ __forceinline__ unsigned pkbf(float a, float b) {
    float2 f; f.x = a; f.y = b;
    __hip_bfloat162 h = __float22bfloat162_rn(f);
    union { __hip_bfloat162 h2; unsigned u; } c;
    c.h2 = h;
    return c.u;
}
__device__ __forceinline__ void gl_lds16(const unsigned short* g, unsigned short* l) {
    __builtin_amdgcn_global_load_lds((const __attribute__((address_space(1))) void*)g,
                                     (__attribute__((address_space(3))) void*)l, 16, 0, 0);
}
// bf16 iff "exponent" bits of low halfword concentrate in the normal range.
__device__ __forceinline__ int detect_bf(const void* bias, int lane) {
    unsigned w = ((const unsigned*)bias)[lane];
    unsigned e = (w >> 7) & 0xFF;
    unsigned long long m = __ballot(e >= 100 && e <= 135);
    return __popcll(m) >= 48;
}

// In-register S^T -> PV-B-fragment exchange.
__device__ __forceinline__ void plswap(unsigned x, unsigned& y0, unsigned& y1) {
    unsigned aa = x, bb = x;
    asm("v_permlane32_swap_b32 %0, %1" : "+v"(aa), "+v"(bb));
    asm("v_permlane16_swap_b32 %0, %1" : "+v"(aa), "+v"(bb));
    y0 = aa; y1 = bb;
}
__device__ __forceinline__ bf16x8 xfrag(unsigned x00, unsigned x01,
                                        unsigned x10, unsigned x11, int qsel) {
    unsigned y000, y100, y001, y101, y010, y110, y011, y111;
    plswap(x00, y000, y100);
    plswap(x01, y001, y101);
    plswap(x10, y010, y110);
    plswap(x11, y011, y111);
    union { unsigned u[4]; bf16x8 v; } r;
    r.u[0] = qsel ? y010 : y000;
    r.u[1] = qsel ? y011 : y001;
    r.u[2] = qsel ? y110 : y100;
    r.u[3] = qsel ? y111 : y101;
    return r.v;
}

// prep: 768 blocks. Each transposes one w tile; fp32 path converts x stripes
// bid, bid+768, bid+1536 with float4 loads.
__global__ __launch_bounds__(256) void k_prep(const void* __restrict__ w,
                                              const void* __restrict__ x,
                                              const void* __restrict__ bias,
                                              unsigned short* __restrict__ wt,
                                              unsigned short* __restrict__ xb) {
    __shared__ unsigned short tile[64 * 66];
    int t = threadIdx.x;
    int isbf = detect_bf(bias, t & 63);
    int bid = blockIdx.x;

    {
        int n0 = (bid % 48) * 64;
        int k0 = (bid / 48) * 64;
        for (int i = 0; i < 16; ++i) {
            int idx = t + i * 256;
            int r = idx >> 6, c = idx & 63;
            unsigned short v;
            if (isbf) v = ((const unsigned short*)w)[(k0 + r) * C3 + n0 + c];
            else      v = f2b(((const float*)w)[(k0 + r) * C3 + n0 + c]);
            tile[r * 66 + c] = v;
        }
        __syncthreads();
        for (int i = 0; i < 16; ++i) {
            int idx = t + i * 256;
            int r = idx >> 6, c = idx & 63;
            wt[(n0 + r) * CDIM + k0 + c] = tile[c * 66 + r];
        }
    }
    if (!isbf) {
        const float4* s = (const float4*)x;
        uint2* d = (uint2*)xb;
        for (int sb = bid; sb < 2048; sb += 768) {
            int base = sb * 512;           // stripe = 2048 floats = 512 float4
            for (int j = t; j < 512; j += 256) {
                float4 v = s[base + j];
                uint2 o_;
                o_.x = (unsigned)f2b(v.x) | ((unsigned)f2b(v.y) << 16);
                o_.y = (unsigned)f2b(v.z) | ((unsigned)f2b(v.w) << 16);
                d[base + j] = o_;
            }
        }
    }
}

// GEMM v3 (unchanged from R12): 128x128 tile, BK=32, 4 waves, 256 thr.
// Depth-2 gl_lds pipeline, counted vmcnt(4), raw s_barrier, XOR-4 swizzle.
__global__ __launch_bounds__(256, 3) void k_gemm_qkv(const void* __restrict__ xraw,
                                                     const unsigned short* __restrict__ xb,
                                                     const void* __restrict__ biasraw,
                                                     const unsigned short* __restrict__ Bt,
                                                     unsigned short* __restrict__ qk,
                                                     unsigned short* __restrict__ k2,
                                                     unsigned short* __restrict__ v2) {
    __shared__ __align__(16) unsigned short As[2 * 128 * 32];   // 16KB
    __shared__ __align__(16) unsigned short Bs[2 * 128 * 32];   // 16KB
    int tid  = threadIdx.x;
    int lane = tid & 63, wv = tid >> 6;
    int quad = lane >> 4, l16 = lane & 15;
    int isbf = detect_bf(biasraw, lane);
    const unsigned short* A = isbf ? (const unsigned short*)xraw : xb;

    int lin = blockIdx.x + 24 * blockIdx.y;
    int swz = (lin & 7) * 96 + (lin >> 3);
    int m0 = (swz / 24) * 128, n0 = (swz % 24) * 128;
    int wm = (wv >> 1) * 64, wn = (wv & 1) * 64;

    f32x4 acc[4][4] = {};

    int r0 = tid >> 2;
    int g0 = (((tid & 3) ^ (r0 & 3)) * 8);
    const unsigned short* a0 = A  + (m0 + r0) * CDIM + g0;
    const unsigned short* b0 = Bt + (n0 + r0) * CDIM + g0;
    unsigned short* dA = As + tid * 8;
    unsigned short* dB = Bs + tid * 8;

    int sw4 = l16 & 3;
    int aro = (wm + l16) * 32 + ((quad ^ sw4) * 8);
    int bro = (wn + l16) * 32 + ((quad ^ sw4) * 8);

    gl_lds16(a0,                 dA);
    gl_lds16(a0 + 64 * CDIM,     dA + 2048);
    gl_lds16(b0,                 dB);
    gl_lds16(b0 + 64 * CDIM,     dB + 2048);
    gl_lds16(a0 + 32,            dA + 4096);
    gl_lds16(a0 + 64 * CDIM + 32, dA + 4096 + 2048);
    gl_lds16(b0 + 32,            dB + 4096);
    gl_lds16(b0 + 64 * CDIM + 32, dB + 4096 + 2048);
    asm volatile("s_waitcnt vmcnt(4)" ::: "memory");
    __builtin_amdgcn_s_barrier();

    #pragma unroll 2
    for (int kt = 0; kt < 32; ++kt) {
        int cur = kt & 1;
        const unsigned short* Ac = As + cur * 4096;
        const unsigned short* Bc = Bs + cur * 4096;

        bf16x8 af[4], bfv[4];
        #pragma unroll
        for (int mt = 0; mt < 4; ++mt)
            af[mt] = *(const bf16x8*)&Ac[aro + mt * 512];
        #pragma unroll
        for (int nt = 0; nt < 4; ++nt)
            bfv[nt] = *(const bf16x8*)&Bc[bro + nt * 512];

        __builtin_amdgcn_s_setprio(1);
        #pragma unroll
        for (int mt = 0; mt < 4; ++mt)
            #pragma unroll
            for (int nt = 0; nt < 4; ++nt)
                acc[mt][nt] = __builtin_amdgcn_mfma_f32_16x16x32_bf16(af[mt], bfv[nt], acc[mt][nt], 0, 0, 0);
        __builtin_amdgcn_s_setprio(0);

        __builtin_amdgcn_s_barrier();
        if (kt < 30) {
            int koff = (kt + 2) * 32;
            unsigned short* tA = As + cur * 4096;
            unsigned short* tB = Bs + cur * 4096;
            gl_lds16(a0 + koff,            tA + tid * 8);
            gl_lds16(a0 + 64 * CDIM + koff, tA + tid * 8 + 2048);
            gl_lds16(b0 + koff,            tB + tid * 8);
            gl_lds16(b0 + 64 * CDIM + koff, tB + tid * 8 + 2048);
            asm volatile("s_waitcnt vmcnt(4)" ::: "memory");
        } else {
            asm volatile("s_waitcnt vmcnt(0)" ::: "memory");
        }
        __builtin_amdgcn_s_barrier();
    }

    if (n0 < 1024) {
        for (int mt = 0; mt < 4; ++mt) {
            int row = m0 + wm + mt * 16 + quad * 4;
            for (int nt = 0; nt < 4; ++nt) {
                int col = n0 + wn + nt * 16 + l16;
                float bv = isbf ? b2f(((const unsigned short*)biasraw)[col])
                                : ((const float*)biasraw)[col];
                for (int i = 0; i < 4; ++i)
                    qk[(row + i) * 2048 + col] = f2b(acc[mt][nt][i] + bv);
            }
        }
    } else if (n0 < 2048) {
        for (int mt = 0; mt < 4; ++mt) {
            int row = m0 + wm + mt * 16 + quad * 4;
            int tq = row & 2047, b = row >> 11;
            for (int nt = 0; nt < 4; ++nt) {
                int col = n0 + wn + nt * 16 + l16;
                float bv = isbf ? b2f(((const unsigned short*)biasraw)[col])
                                : ((const float*)biasraw)[col];
                int c = col - 1024;
                int hh = c >> 6, d = c & 63;
                int base = ((b * 16 + hh) * 32 + (tq >> 6)) * 4096
                         + ((tq >> 5) & 1) * 2048 + ((tq >> 4) & 1) * 1024
                         + (d >> 5) * 512 + ((d >> 3) & 3) * 128
                         + (tq & 15) * 8 + (d & 7);
                for (int i = 0; i < 4; ++i)
                    k2[base + i * 8] = f2b(acc[mt][nt][i] + bv);
            }
        }
    } else {
        for (int mt = 0; mt < 4; ++mt) {
            int row = m0 + wm + mt * 16 + quad * 4;
            int tq = row & 2047, b = row >> 11;
            for (int nt = 0; nt < 4; ++nt) {
                int col = n0 + wn + nt * 16 + l16;
                float bv = isbf ? b2f(((const unsigned short*)biasraw)[col])
                                : ((const float*)biasraw)[col];
                int c = col - 2048;
                int hh = c >> 6, d = c & 63;
                int base = ((b * 16 + hh) * 32 + (tq >> 6)) * 4096
                         + ((tq >> 5) & 1) * 2048 + (d >> 4) * 512
                         + ((tq >> 3) & 3) * 128 + (d & 15) * 8 + (tq & 7);
                u16x4 pk;
                for (int i = 0; i < 4; ++i) pk[i] = f2b(acc[mt][nt][i] + bv);
                *(u16x4*)&v2[base] = pk;
            }
        }
    }
}

// Split-kv causal flash attention v11. Grid (32 bh, 32 y), 4 waves/block, 256 thr.
// v10 + cross-trip pipeline: at entry to trip t, svIN holds scores(t) (computed
// last trip) and kf holds K(t+1) frags (loaded last trip). Body: load V(t);
// QK(t+1)->svOUT (matrix pipe, no load dep); load K(t+2); softmax(svIN,t);
// xfrag+PV. 2x-unrolled ping-pong avoids register copies.
__global__ __launch_bounds__(256, 3) void k_attn(const unsigned short* __restrict__ qk,
                                                 const unsigned short* __restrict__ k2,
                                                 const unsigned short* __restrict__ v2,
                                                 const void* __restrict__ biasraw,
                                                 void* __restrict__ outv) {
    __shared__ __align__(16) float SMf[4416];   // 17664B epilogue merge buffer

    int tid  = threadIdx.x;
    int lane = tid & 63, wv = tid >> 6;            // wv 0..3
    int quad = lane >> 4, l16 = lane & 15;
    int isbf = detect_bf(biasraw, lane);
    int bh = blockIdx.x;
    int g  = 31 - blockIdx.y;                      // longest blocks dispatch first
    int b = bh >> 4, h = bh & 15;
    int rowbase = b * TLEN;

    int s_ = wv >> 1;                              // q sub-band (0/1)
    int p  = wv & 1;                               // kv parity
    int qbase = 64 * g + 32 * s_;
    int T  = g + 1;
    int Tw = T - ((s_ == 0 && p == 1) ? 1 : 0);    // (0,1) skips the diagonal trip
    bool dmw = (p == s_);                          // wave masks on its last trip

    bf16x8 qf[2][2];
    for (int qt = 0; qt < 2; ++qt)
        for (int kh = 0; kh < 2; ++kh)
            qf[qt][kh] = *(const bf16x8*)&qk[(rowbase + qbase + qt * 16 + l16) * 2048
                                            + h * HS + kh * 32 + quad * 8];

    f32x4 o[2][4] = {};
    float ls[2] = {0.f, 0.f};

    const unsigned short* kp = k2 + bh * 131072 + p * 2048 + lane * 8;
    const unsigned short* vp = v2 + bh * 131072 + p * 2048 + lane * 8;

    // pipeline state: kf = K(t+1) frags; svA/svB = score ping-pong
    bf16x8 kf00, kf01, kf10, kf11;
    f32x4 svA[2][2], svB[2][2];
    {
        bf16x8 k0a = *(const bf16x8*)kp;
        bf16x8 k0b = *(const bf16x8*)(kp + 512);
        bf16x8 k0c = *(const bf16x8*)(kp + 1024);
        bf16x8 k0d = *(const bf16x8*)(kp + 1536);
        kp += 4096;
        kf00 = *(const bf16x8*)kp;
        kf01 = *(const bf16x8*)(kp + 512);
        kf10 = *(const bf16x8*)(kp + 1024);
        kf11 = *(const bf16x8*)(kp + 1536);
        kp += 4096;
        #pragma unroll
        for (int qt = 0; qt < 2; ++qt) {
            f32x4 z0 = {};
            z0 = __builtin_amdgcn_mfma_f32_16x16x32_bf16(k0a, qf[qt][0], z0, 0, 0, 0);
            z0 = __builtin_amdgcn_mfma_f32_16x16x32_bf16(k0b, qf[qt][1], z0, 0, 0, 0);
            svA[qt][0] = z0;
            f32x4 z1 = {};
            z1 = __builtin_amdgcn_mfma_f32_16x16x32_bf16(k0c, qf[qt][0], z1, 0, 0, 0);
            z1 = __builtin_amdgcn_mfma_f32_16x16x32_bf16(k0d, qf[qt][1], z1, 0, 0, 0);
            svA[qt][1] = z1;
        }
    }

    auto trip = [&](f32x4 (&svin)[2][2], f32x4 (&svout)[2][2], int tt) {
        // V fragments for this trip (consumed after softmax)
        bf16x8 av0 = *(const bf16x8*)vp;
        bf16x8 av1 = *(const bf16x8*)(vp + 512);
        bf16x8 av2 = *(const bf16x8*)(vp + 1024);
        bf16x8 av3 = *(const bf16x8*)(vp + 1536);
        vp += 4096;

        // QK for trip tt+1 (frags prefetched last trip -> no load dependence);
        // runs on the matrix pipe under this trip's softmax VALU.
        __builtin_amdgcn_s_setprio(1);
        #pragma unroll
        for (int qt = 0; qt < 2; ++qt) {
            f32x4 z0 = {};
            z0 = __builtin_amdgcn_mfma_f32_16x16x32_bf16(kf00, qf[qt][0], z0, 0, 0, 0);
            z0 = __builtin_amdgcn_mfma_f32_16x16x32_bf16(kf01, qf[qt][1], z0, 0, 0, 0);
            svout[qt][0] = z0;
            f32x4 z1 = {};
            z1 = __builtin_amdgcn_mfma_f32_16x16x32_bf16(kf10, qf[qt][0], z1, 0, 0, 0);
            z1 = __builtin_amdgcn_mfma_f32_16x16x32_bf16(kf11, qf[qt][1], z1, 0, 0, 0);
            svout[qt][1] = z1;
        }
        __builtin_amdgcn_s_setprio(0);

        // load K(tt+2) (unconditional; one-past-end lands in allocated ws)
        kf00 = *(const bf16x8*)kp;
        kf01 = *(const bf16x8*)(kp + 512);
        kf10 = *(const bf16x8*)(kp + 1024);
        kf11 = *(const bf16x8*)(kp + 1536);
        kp += 4096;

        // fixed-max softmax on svin (trip tt): pv = 2^(s*SCL - 12)
        unsigned sp[2][2][2];
        int kvb = tt * KVT + 32 * p;
        if (dmw && tt == T - 1) {
            #pragma unroll
            for (int qt = 0; qt < 2; ++qt) {
                float psum = 0.f;
                int q = qbase + qt * 16 + l16;
                #pragma unroll
                for (int nt = 0; nt < 2; ++nt) {
                    float pv[4];
                    #pragma unroll
                    for (int i = 0; i < 4; ++i) {
                        float arg = fmaf(svin[qt][nt][i], SCL, -12.0f);
                        int kv = kvb + nt * 16 + quad * 4 + i;
                        if (kv > q) arg = -1e30f;
                        pv[i] = fexp2(arg);
                        psum += pv[i];
                    }
                    sp[qt][nt][0] = pkbf(pv[0], pv[1]);
                    sp[qt][nt][1] = pkbf(pv[2], pv[3]);
                }
                ls[qt] += psum;
            }
        } else {
            #pragma unroll
            for (int qt = 0; qt < 2; ++qt) {
                float psum = 0.f;
                #pragma unroll
                for (int nt = 0; nt < 2; ++nt) {
                    float pv[4];
                    #pragma unroll
                    for (int i = 0; i < 4; ++i) {
                        float arg = fmaf(svin[qt][nt][i], SCL, -12.0f);
                        pv[i] = fexp2(arg);
                        psum += pv[i];
                    }
                    sp[qt][nt][0] = pkbf(pv[0], pv[1]);
                    sp[qt][nt][1] = pkbf(pv[2], pv[3]);
                }
                ls[qt] += psum;
            }
        }

        // O^T += V^T.P^T
        int qsel = quad & 2;
        bf16x8 f0 = xfrag(sp[0][0][0], sp[0][0][1], sp[0][1][0], sp[0][1][1], qsel);
        bf16x8 f1 = xfrag(sp[1][0][0], sp[1][0][1], sp[1][1][0], sp[1][1][1], qsel);
        __builtin_amdgcn_s_setprio(1);
        o[0][0] = __builtin_amdgcn_mfma_f32_16x16x32_bf16(av0, f0, o[0][0], 0, 0, 0);
        o[1][0] = __builtin_amdgcn_mfma_f32_16x16x32_bf16(av0, f1, o[1][0], 0, 0, 0);
        o[0][1] = __builtin_amdgcn_mfma_f32_16x16x32_bf16(av1, f0, o[0][1], 0, 0, 0);
        o[1][1] = __builtin_amdgcn_mfma_f32_16x16x32_bf16(av1, f1, o[1][1], 0, 0, 0);
        o[0][2] = __builtin_amdgcn_mfma_f32_16x16x32_bf16(av2, f0, o[0][2], 0, 0, 0);
        o[1][2] = __builtin_amdgcn_mfma_f32_16x16x32_bf16(av2, f1, o[1][2], 0, 0, 0);
        o[0][3] = __builtin_amdgcn_mfma_f32_16x16x32_bf16(av3, f0, o[0][3], 0, 0, 0);
        o[1][3] = __builtin_amdgcn_mfma_f32_16x16x32_bf16(av3, f1, o[1][3], 0, 0, 0);
        __builtin_amdgcn_s_setprio(0);
    };

    int t = 0;
    for (; t + 2 <= Tw; t += 2) {
        trip(svA, svB, t);
        trip(svB, svA, t + 1);
    }
    if (t < Tw) trip(svA, svB, t);

    // merge the two kv-parity partials (additive: same fixed-max scale), normalize, store
    #pragma unroll
    for (int qt = 0; qt < 2; ++qt) {
        ls[qt] += __shfl_xor(ls[qt], 16);
        ls[qt] += __shfl_xor(ls[qt], 32);
    }
    float* mrg  = SMf;
    float* lbuf = SMf + 4352;

    if (p == 1) {
        #pragma unroll
        for (int qt = 0; qt < 2; ++qt)
            #pragma unroll
            for (int dt = 0; dt < 4; ++dt)
                *(f32x4*)&mrg[s_ * (32 * 68) + (qt * 16 + l16) * 68 + dt * 16 + quad * 4] = o[qt][dt];
        if (quad == 0) {
            lbuf[s_ * 32 + l16]      = ls[0];
            lbuf[s_ * 32 + 16 + l16] = ls[1];
        }
    }
    __syncthreads();
    if (p == 0) {
        #pragma unroll
        for (int qt = 0; qt < 2; ++qt) {
            float lt = ls[qt] + lbuf[s_ * 32 + qt * 16 + l16];
            float inv = 1.0f / lt;
            int q = qbase + qt * 16 + l16;
            if (isbf) {
                unsigned short* out = (unsigned short*)outv;
                #pragma unroll
                for (int dt = 0; dt < 4; ++dt) {
                    f32x4 m = *(const f32x4*)&mrg[s_ * (32 * 68) + (qt * 16 + l16) * 68 + dt * 16 + quad * 4];
                    u16x4 ov;
                    #pragma unroll
                    for (int i = 0; i < 4; ++i) ov[i] = f2b((o[qt][dt][i] + m[i]) * inv);
                    *(u16x4*)&out[(rowbase + q) * CDIM + h * HS + dt * 16 + quad * 4] = ov;
                }
            } else {
                float* out = (float*)outv;
                #pragma unroll
                for (int dt = 0; dt < 4; ++dt) {
                    f32x4 m = *(const f32x4*)&mrg[s_ * (32 * 68) + (qt * 16 + l16) * 68 + dt * 16 + quad * 4];
                    float4 ov;
                    ov.x = (o[qt][dt][0] + m[0]) * inv;
                    ov.y = (o[qt][dt][1] + m[1]) * inv;
                    ov.z = (o[qt][dt][2] + m[2]) * inv;
                    ov.w = (o[qt][dt][3] + m[3]) * inv;
                    *(float4*)&out[(rowbase + q) * CDIM + h * HS + dt * 16 + quad * 4] = ov;
                }
            }
        }
    }
}

extern "C" void kernel_launch(void* const* d_in, const int* in_sizes, int n_in,
                              void* d_out, int out_size, void* d_ws, size_t ws_size,
                              hipStream_t stream) {
    const void* x    = d_in[0];
    const void* w    = d_in[1];
    const void* bias = d_in[2];

    char* ws = (char*)d_ws;
    unsigned short* xb  = (unsigned short*)ws;                   // 8 MB (fp32 path only)
    unsigned short* wt  = (unsigned short*)(ws + (8u  << 20));   // 6 MB
    unsigned short* qk  = (unsigned short*)(ws + (16u << 20));   // 16 MB (Q rows)
    unsigned short* k2  = (unsigned short*)(ws + (32u << 20));   // 8 MB (K fragment-order)
    unsigned short* v2  = (unsigned short*)(ws + (40u << 20));   // 8 MB (V fragment-order)

    k_prep<<<768, 256, 0, stream>>>(w, x, bias, wt, xb);
    k_gemm_qkv<<<dim3(24, 32), 256, 0, stream>>>(x, xb, bias, wt, qk, k2, v2);
    k_attn<<<dim3(32, 32), 256, 0, stream>>>(qk, k2, v2, bias, d_out);
}